// Round 1
// baseline (195.433 us; speedup 1.0000x reference)
//
#include <hip/hip_runtime.h>
#include <hip/hip_bf16.h>

#define Bdim 4096
#define Ldim 4096
#define Hdim 1024
#define TILE 128
#define BK 32

typedef __attribute__((ext_vector_type(8))) __bf16 bf16x8;
typedef __attribute__((ext_vector_type(4))) float floatx4;

__device__ __forceinline__ unsigned short f2bf(float f) {
  union { __hip_bfloat16 h; unsigned short u; } c;
  c.h = __float2bfloat16(f);
  return c.u;
}

// ---- X fp32 -> bf16 ----------------------------------------------------
__global__ __launch_bounds__(256) void cvt_x_kernel(const float* __restrict__ X,
                                                    unsigned short* __restrict__ Xb) {
  int i = blockIdx.x * 256 + threadIdx.x;
  float4 v = reinterpret_cast<const float4*>(X)[i];
  ushort4 o;
  o.x = f2bf(v.x); o.y = f2bf(v.y); o.z = f2bf(v.z); o.w = f2bf(v.w);
  reinterpret_cast<ushort4*>(Xb)[i] = o;
}

// ---- W fp32 -> bf16, fused bias[l] = sum_h E*W + b ---------------------
__global__ __launch_bounds__(256) void cvt_w_bias_kernel(
    const float* __restrict__ W, const float* __restrict__ E,
    const float* __restrict__ b, unsigned short* __restrict__ Wb,
    float* __restrict__ bias) {
  int row = blockIdx.x;            // 0..Ldim-1
  int t = threadIdx.x;             // 0..255, each owns one float4 of the 1024-row
  const float4 wv = reinterpret_cast<const float4*>(W + (size_t)row * Hdim)[t];
  const float4 ev = reinterpret_cast<const float4*>(E + (size_t)row * Hdim)[t];
  ushort4 o;
  o.x = f2bf(wv.x); o.y = f2bf(wv.y); o.z = f2bf(wv.z); o.w = f2bf(wv.w);
  reinterpret_cast<ushort4*>(Wb + (size_t)row * Hdim)[t] = o;
  float dot = wv.x * ev.x + wv.y * ev.y + wv.z * ev.z + wv.w * ev.w;
#pragma unroll
  for (int off = 32; off > 0; off >>= 1) dot += __shfl_down(dot, off, 64);
  __shared__ float part[4];
  if ((t & 63) == 0) part[t >> 6] = dot;
  __syncthreads();
  if (t == 0) bias[row] = part[0] + part[1] + part[2] + part[3] + b[row];
}

// ---- C[B,L] = Xb @ Wb^T + bias -----------------------------------------
// 128x128 tile, BK=32, 4 waves, each wave 64x64 via 4x4 MFMA 16x16x32 tiles.
__global__ __launch_bounds__(256) void gemm_bias_kernel(
    const unsigned short* __restrict__ A,   // [Bdim][Hdim] bf16 bits
    const unsigned short* __restrict__ Bw,  // [Ldim][Hdim] bf16 bits
    const float* __restrict__ bias,         // [Ldim]
    float* __restrict__ C) {                // [Bdim][Ldim] fp32
  __shared__ __align__(16) unsigned short lA[TILE * BK];
  __shared__ __align__(16) unsigned short lB[TILE * BK];

  const int tid = threadIdx.x;
  const int wave = tid >> 6;
  const int lane = tid & 63;
  const int m_blk = blockIdx.y * TILE;
  const int n_blk = blockIdx.x * TILE;

  // staging: wave stages rows [wave*32, wave*32+32) of A-tile and B-tile.
  // One global_load_lds(16B) covers 16 rows (16 rows * 64 B = 1024 B = 64 lanes * 16 B).
  const int srow = wave * 32 + (lane >> 2);
  const unsigned short* gA = A + (size_t)(m_blk + srow) * Hdim + (lane & 3) * 8;
  const unsigned short* gB = Bw + (size_t)(n_blk + srow) * Hdim + (lane & 3) * 8;
  unsigned short* lA0 = lA + (wave * 32) * BK;   // wave-uniform LDS base
  unsigned short* lB0 = lB + (wave * 32) * BK;

  // compute sub-tile origin for this wave
  const int wm = (wave >> 1) * 64;
  const int wn = (wave & 1) * 64;
  const int fr = lane & 15;   // row (A) / col (B) within 16x16 frag
  const int fq = lane >> 4;   // k-chunk quad
  const unsigned short* pa = lA + (wm + fr) * BK + fq * 8;
  const unsigned short* pb = lB + (wn + fr) * BK + fq * 8;

  floatx4 acc[4][4] = {};

  for (int kt = 0; kt < Hdim / BK; ++kt) {
    __syncthreads();  // previous iter done reading LDS
    __builtin_amdgcn_global_load_lds(
        (const __attribute__((address_space(1))) void*)gA,
        (__attribute__((address_space(3))) void*)lA0, 16, 0, 0);
    __builtin_amdgcn_global_load_lds(
        (const __attribute__((address_space(1))) void*)(gA + 16 * Hdim),
        (__attribute__((address_space(3))) void*)(lA0 + 16 * BK), 16, 0, 0);
    __builtin_amdgcn_global_load_lds(
        (const __attribute__((address_space(1))) void*)gB,
        (__attribute__((address_space(3))) void*)lB0, 16, 0, 0);
    __builtin_amdgcn_global_load_lds(
        (const __attribute__((address_space(1))) void*)(gB + 16 * Hdim),
        (__attribute__((address_space(3))) void*)(lB0 + 16 * BK), 16, 0, 0);
    gA += BK;
    gB += BK;
    __syncthreads();  // staging visible (compiler drains vmcnt before s_barrier)

    bf16x8 af[4], bfr[4];
#pragma unroll
    for (int i = 0; i < 4; ++i) {
      af[i]  = *reinterpret_cast<const bf16x8*>(pa + i * 16 * BK);
      bfr[i] = *reinterpret_cast<const bf16x8*>(pb + i * 16 * BK);
    }
#pragma unroll
    for (int mi = 0; mi < 4; ++mi)
#pragma unroll
      for (int ni = 0; ni < 4; ++ni)
        acc[mi][ni] = __builtin_amdgcn_mfma_f32_16x16x32_bf16(
            af[mi], bfr[ni], acc[mi][ni], 0, 0, 0);
  }

  // epilogue: C/D layout col=lane&15, row=(lane>>4)*4+reg  [m89-verified]
  const int col0 = n_blk + wn + fr;
  const int row0 = m_blk + wm + fq * 4;
#pragma unroll
  for (int ni = 0; ni < 4; ++ni) {
    const float bs = bias[col0 + ni * 16];
#pragma unroll
    for (int mi = 0; mi < 4; ++mi) {
      float* cp = C + (size_t)(row0 + mi * 16) * Ldim + (col0 + ni * 16);
      floatx4 v = acc[mi][ni];
      cp[0 * (size_t)Ldim] = v.x + bs;
      cp[1 * (size_t)Ldim] = v.y + bs;
      cp[2 * (size_t)Ldim] = v.z + bs;
      cp[3 * (size_t)Ldim] = v.w + bs;
    }
  }
}

extern "C" void kernel_launch(void* const* d_in, const int* in_sizes, int n_in,
                              void* d_out, int out_size, void* d_ws, size_t ws_size,
                              hipStream_t stream) {
  const float* X = (const float*)d_in[0];  // bert_output [B,H]
  const float* E = (const float*)d_in[1];  // label_embed [L,H]
  const float* W = (const float*)d_in[2];  // W [L,H]
  const float* b = (const float*)d_in[3];  // b [L]
  // d_in[4] = labels, unused by the reference output.
  float* out = (float*)d_out;

  unsigned short* Xb = (unsigned short*)d_ws;                 // 8 MB
  unsigned short* Wb = Xb + (size_t)Bdim * Hdim;              // 8 MB
  float* bias = (float*)(Wb + (size_t)Ldim * Hdim);           // 16 KB

  cvt_x_kernel<<<(Bdim * Hdim / 4) / 256, 256, 0, stream>>>(X, Xb);
  cvt_w_bias_kernel<<<Ldim, 256, 0, stream>>>(W, E, b, Wb, bias);
  dim3 grid(Ldim / TILE, Bdim / TILE);
  gemm_bias_kernel<<<grid, 256, 0, stream>>>(Xb, Wb, bias, out);
}